// Round 8
// baseline (3246.510 us; speedup 1.0000x reference)
//
#include <hip/hip_runtime.h>
#include <float.h>
#include <math.h>

#define B_    128
#define H_    512
#define V_    1000
#define T_    256
#define G4_   2048
#define NBLK  256          // cooperative launch: 1 block/CU
#define SPIN_MAX (1 << 17) // bounded spin: converts would-be hang into wrong-answer

#define AT_LOAD(p)    __hip_atomic_load((p), __ATOMIC_RELAXED, __HIP_MEMORY_SCOPE_AGENT)
#define AT_STORE(p,v) __hip_atomic_store((p), (v), __ATOMIC_RELAXED, __HIP_MEMORY_SCOPE_AGENT)

// Pin a float4 in VGPRs (r7: kept RA from folding weight loads into the loop).
#define PIN4(v_) asm volatile("" : "+v"((v_).x), "+v"((v_).y), "+v"((v_).z), "+v"((v_).w))

__device__ __forceinline__ float dot4(float4 a, float4 b, float acc) {
  return fmaf(a.x, b.x, fmaf(a.y, b.y, fmaf(a.z, b.z, fmaf(a.w, b.w, acc))));
}

// 16-lane butterfly sum, pure DPP (VALU pipe, zero LDS traffic).
__device__ __forceinline__ float red16(float x) {
  x += __int_as_float(__builtin_amdgcn_mov_dpp(__float_as_int(x), 0xB1,  0xF, 0xF, true));
  x += __int_as_float(__builtin_amdgcn_mov_dpp(__float_as_int(x), 0x4E,  0xF, 0xF, true));
  x += __int_as_float(__builtin_amdgcn_mov_dpp(__float_as_int(x), 0x141, 0xF, 0xF, true));
  x += __int_as_float(__builtin_amdgcn_mov_dpp(__float_as_int(x), 0x140, 0xF, 0xF, true));
  return x;
}

// Fast overflow-safe transcendentals (library tanhf/expf are multi-op calls;
// these map to v_exp_f32/v_rcp_f32).  sigmoid: exp(-x)->inf => 0, ->0 => 1. OK.
// tanh via |x|: e=exp(2|x|)->inf => r->1; sign restored with copysignf. OK.
__device__ __forceinline__ float fsigmoid(float x) {
  return 1.f / (1.f + __expf(-x));
}
__device__ __forceinline__ float ftanh(float x) {
  const float e = __expf(2.f * fabsf(x));
  return copysignf(1.f - 2.f / (e + 1.f), x);
}

// ---------------------------------------------------------------------------
// Precompute GEMM:  C = A[M][0:512] * Bm[N][koff:+512]^T (+bias1+bias2).
// ileave=1 stores gate-interleaved: C[m][ (n&511)*4 + (n>>9) ]  (ldc=2048).
// ---------------------------------------------------------------------------
__global__ __launch_bounds__(256) void gemm_nt_k512(
    const float* __restrict__ A, int M,
    const float* __restrict__ Bm, int ldb, int koff,
    const float* __restrict__ bias1, const float* __restrict__ bias2,
    float* __restrict__ C, int ldc, int ileave)
{
  __shared__ float As[16][68];
  __shared__ float Bs[16][68];
  const int tid = threadIdx.x;
  const int m0 = blockIdx.y * 64, n0 = blockIdx.x * 64;
  const int tm = tid & 15, tn = tid >> 4;
  const int lm = tid & 63, kq = tid >> 6;
  float acc[4][4] = {};
  for (int k0 = 0; k0 < 512; k0 += 16) {
    float4 av = make_float4(0.f, 0.f, 0.f, 0.f);
    if (m0 + lm < M) av = *(const float4*)(A + (size_t)(m0 + lm) * 512 + k0 + kq * 4);
    float4 bv = *(const float4*)(Bm + (size_t)(n0 + lm) * ldb + koff + k0 + kq * 4);
    __syncthreads();
    As[kq*4+0][lm] = av.x; As[kq*4+1][lm] = av.y; As[kq*4+2][lm] = av.z; As[kq*4+3][lm] = av.w;
    Bs[kq*4+0][lm] = bv.x; Bs[kq*4+1][lm] = bv.y; Bs[kq*4+2][lm] = bv.z; Bs[kq*4+3][lm] = bv.w;
    __syncthreads();
#pragma unroll
    for (int kk = 0; kk < 16; ++kk) {
      const float4 a = *(const float4*)&As[kk][tm * 4];
      const float4 b = *(const float4*)&Bs[kk][tn * 4];
      const float aa[4] = {a.x, a.y, a.z, a.w};
      const float bb[4] = {b.x, b.y, b.z, b.w};
#pragma unroll
      for (int i = 0; i < 4; ++i)
#pragma unroll
        for (int j = 0; j < 4; ++j)
          acc[i][j] = fmaf(aa[i], bb[j], acc[i][j]);
    }
  }
#pragma unroll
  for (int i = 0; i < 4; ++i) {
    const int m = m0 + tm * 4 + i;
    if (m < M) {
#pragma unroll
      for (int j = 0; j < 4; ++j) {
        const int n = n0 + tn * 4 + j;
        float v = acc[i][j];
        if (bias1) v += bias1[n];
        if (bias2) v += bias2[n];
        const size_t idx = ileave ? ((size_t)m * ldc + (size_t)(n & 511) * 4 + (n >> 9))
                                  : ((size_t)m * ldc + n);
        C[idx] = v;
      }
    }
  }
}

// ---------------------------------------------------------------------------
// amax word: [val:f32 bits in high 32][tag:16][token:16]; tag(t) = t+2.
// ---------------------------------------------------------------------------
__global__ __launch_bounds__(256) void init_kernel(
    const float* __restrict__ ctx, float* __restrict__ hbuf,
    unsigned long long* __restrict__ amax,
    int* __restrict__ hdone, const int* __restrict__ start_id)
{
  const int i = blockIdx.x * blockDim.x + threadIdx.x;
  // h(-1) = context into slot 1
  ((float4*)(hbuf + B_ * H_))[i] = ((const float4*)ctx)[i];
  if (i < B_ * 32) {
    const int m = i & 31;
    const unsigned long long w = (m == 0)
        ? ((((unsigned long long)__float_as_uint(FLT_MAX)) << 32) |
           (1u << 16) | (unsigned)(*start_id))
        : ((((unsigned long long)__float_as_uint(-FLT_MAX)) << 32) | (1u << 16));
    amax[(size_t)B_ * 32 + i] = w;   // parity-1 slot, tag(-1)=1
  }
  if (i < 2 * 8 * 32) hdone[i * 16] = 0;
}

// ---------------------------------------------------------------------------
// Persistent cooperative decoder, 1024 threads (16 waves, 4/SIMD).
// 8 groups x 32 blocks; group g owns rows [16g,16g+16).  Tagged-dataflow sync.
//
// Round-8 structure:
//  * K-QUARTER split: wave w -> (blk = w&3 gate/vocab-octet, par2 = w>>2
//    K-quarter).  Lane (q1=lane>>4, kc=lane&15) owns 8-float K-chunks ->
//    weights 48 VGPR/lane (w1r 32 + w2r 16), fits the 128-VGPR cap of
//    1024-thread blocks.  4 waves/SIMD double the stall hiding that r7's
//    69% VALUBusy showed was the limiter.
//  * Cross-parity combine over 4 planes (gbuf4/lbuf4), summed in D/H.
//  * hs stride-20 chunk layout IDENTICAL to r7 (16-float chunks; a lane
//    reads half a chunk: col = chunk16*20 + (kc&1)*8) -> staging unchanged,
//    reads <=2-way.
//  * r5/r7 phase order (P1 -> poll -> D -> exchange -> P2 -> H).
//  * Fast transcendentals in D (__expf-based sigmoid/tanh, overflow-safe).
//  * Fault-proofed: bounded spins + token clamp.
// ---------------------------------------------------------------------------
__global__ __launch_bounds__(1024) void decoder_main(
    const float* __restrict__ Whh,
    const float* __restrict__ Wout,
    const float* __restrict__ bout,
    const float* __restrict__ proj,
    const float* __restrict__ basep,
    float* __restrict__ hbuf,
    unsigned long long* __restrict__ amax,
    int* __restrict__ hdone,
    float* __restrict__ out)
{
  __shared__ struct alignas(16) SM {
    float hs[16][640];          // h tile: chunk cc at col cc*20 (16 used, 4 pad)
    float gbase[16][68];        // interleaved basep slice [r][u*4+g]
    float gbuf4[4][16][68];     // gate partials per K-quarter
    float lbuf4[4][16][34];     // logit partials per K-quarter
    float sbout[32];
    int   tok[16];
  } sm;

  const int tid  = threadIdx.x;
  const int bid  = blockIdx.x;
  const int gid  = bid >> 5;     // group: rows [16g, 16g+16)
  const int mem  = bid & 31;     // member: units [16*mem,+16) / vocab [32*mem,+32)
  const int lane = tid & 63;
  const int w    = tid >> 6;     // wave 0..15
  const int row_base = gid * 16;
  const int vb   = mem * 32;

  const int q1   = lane >> 4;    // 0..3
  const int kc   = lane & 15;    // 8-float K-chunk within the K-quarter
  const int blk  = w & 3;        // gate index / vocab-octet
  const int par2 = w >> 2;       // K-quarter 0..3
  const int hoff = par2 * 128 + kc * 8;                 // weight K offset
  const int hcol = (par2 * 8 + (kc >> 1)) * 20 + (kc & 1) * 8;  // hs column

  // ---- one-time preloads: weights -> registers, PINNED (48 VGPR) ---------
  float4 w1r[4][2];              // 4 gate-lines x 8 floats
#pragma unroll
  for (int i = 0; i < 4; ++i) {
    const float* p = Whh + (size_t)(blk * 512 + mem * 16 + q1 * 4 + i) * H_ + hoff;
    w1r[i][0] = *(const float4*)(p);
    w1r[i][1] = *(const float4*)(p + 4);
  }
  const int v0 = vb + blk * 8 + q1 * 2;
  float4 w2r[2][2];              // 2 vocab x 8 floats
#pragma unroll
  for (int jj = 0; jj < 2; ++jj) {
    const int vv = (v0 + jj < V_) ? (v0 + jj) : (V_ - 1);
    const float* p = Wout + (size_t)vv * H_ + hoff;
    w2r[jj][0] = *(const float4*)(p);
    w2r[jj][1] = *(const float4*)(p + 4);
  }
#pragma unroll
  for (int i = 0; i < 4; ++i) { PIN4(w1r[i][0]); PIN4(w1r[i][1]); }
#pragma unroll
  for (int jj = 0; jj < 2; ++jj) { PIN4(w2r[jj][0]); PIN4(w2r[jj][1]); }

  // basep slice (interleaved) -> LDS (1 elem/thread); bout slice -> LDS
  {
    const int r = tid >> 6, c = tid & 63;
    sm.gbase[r][c] = basep[(size_t)(row_base + r) * G4_ + mem * 64 + c];
  }
  if (tid < 32) sm.sbout[tid] = (vb + tid < V_) ? bout[vb + tid] : 0.f;

  float c_reg = 0.f;   // tid<256 owns cell (row=row_base+(tid>>4), unit=mem*16+(tid&15))
  const size_t BTVo = (size_t)B_ * T_ * V_;

  // ---- prepass: stage h(-1)=context into hs (stride-20 chunks) -----------
  {
    const unsigned long long* hq =
        (const unsigned long long*)(hbuf + (size_t)B_ * H_ + (size_t)row_base * H_);
    unsigned long long v[4];
#pragma unroll
    for (int i = 0; i < 4; ++i) v[i] = AT_LOAD(&hq[tid + i * 1024]);
#pragma unroll
    for (int i = 0; i < 4; ++i) {
      const int idx = tid + i * 1024;
      const int row = idx >> 8, cp = idx & 255;
      *(unsigned long long*)&sm.hs[row][(cp >> 3) * 20 + (cp & 7) * 2] = v[i];
    }
  }
  __syncthreads();

  for (int t = 0; t < T_; ++t) {
    float* hdst = hbuf + (size_t)(t & 1) * (B_ * H_);

    // ---- P1: gates(t) partials = Whh_quarter * h(t-1) -> gbuf4[par2] -----
#pragma unroll 1
    for (int r = 0; r < 16; ++r) {
      const float* hr = &sm.hs[r][hcol];
      const float4 h0 = *(const float4*)(hr + 0);
      const float4 h1 = *(const float4*)(hr + 4);
      float a0 = dot4(w1r[0][1], h1, dot4(w1r[0][0], h0, 0.f));
      float a1 = dot4(w1r[1][1], h1, dot4(w1r[1][0], h0, 0.f));
      float a2 = dot4(w1r[2][1], h1, dot4(w1r[2][0], h0, 0.f));
      float a3 = dot4(w1r[3][1], h1, dot4(w1r[3][0], h0, 0.f));
      a0 = red16(a0); a1 = red16(a1); a2 = red16(a2); a3 = red16(a3);
      if (kc < 4) {
        const float av = (kc == 0) ? a0 : (kc == 1) ? a1 : (kc == 2) ? a2 : a3;
        sm.gbuf4[par2][r][(q1 * 4 + kc) * 4 + blk] = av;
      }
    }

    // ---- B: poll amax(t-1) -> tok[]  (propagation hidden under P1) ------
    if (tid < 512) {
      const int prow = tid >> 5, pj = tid & 31;
      const unsigned expect = (unsigned)(t + 1) << 16;   // tag(t-1) = t+1
      const unsigned long long* ap =
          amax + ((size_t)((t + 1) & 1) * B_ + row_base + prow) * 32;
      unsigned long long wv = AT_LOAD(&ap[pj]);
      for (int it = 0; (((unsigned)wv ^ expect) & 0xFFFF0000u) && it < SPIN_MAX; ++it) {
        __builtin_amdgcn_s_sleep(1);
        wv = AT_LOAD(&ap[pj]);
      }
      __atomic_signal_fence(__ATOMIC_ACQ_REL);
      float v  = __uint_as_float((unsigned)(wv >> 32));
      int   ix = (int)((unsigned)wv & 0xFFFFu);
#pragma unroll
      for (int d = 16; d >= 1; d >>= 1) {
        const float vo = __shfl_xor(v, d, 32);
        const int   io = __shfl_xor(ix, d, 32);
        if (vo > v || (vo == v && io < ix)) { v = vo; ix = io; }
      }
      if (pj == 0) sm.tok[prow] = (ix >= 0 && ix < V_) ? ix : 0;   // clamp
    }
    __syncthreads();

    // ---- D: LSTM epilogue (tid<256): combine 4 parities + proj + gbase --
    if (tid < 256) {
      const int rl = tid >> 4, ul = tid & 15;
      const int tk = sm.tok[rl];
      const float4 g0 = *(const float4*)&sm.gbuf4[0][rl][ul * 4];
      const float4 g1 = *(const float4*)&sm.gbuf4[1][rl][ul * 4];
      const float4 g2 = *(const float4*)&sm.gbuf4[2][rl][ul * 4];
      const float4 g3 = *(const float4*)&sm.gbuf4[3][rl][ul * 4];
      const float4 gc = *(const float4*)&sm.gbase[rl][ul * 4];
      const float4 gp = *(const float4*)&proj[(size_t)tk * G4_ + (size_t)(mem * 16 + ul) * 4];
      const float gx = (g0.x + g1.x) + (g2.x + g3.x) + gc.x + gp.x;
      const float gy = (g0.y + g1.y) + (g2.y + g3.y) + gc.y + gp.y;
      const float gz = (g0.z + g1.z) + (g2.z + g3.z) + gc.z + gp.z;
      const float gw = (g0.w + g1.w) + (g2.w + g3.w) + gc.w + gp.w;
      const float ig = fsigmoid(gx);
      const float fg = fsigmoid(gy);
      const float gg = ftanh(gz);
      const float og = fsigmoid(gw);
      const float cn = fg * c_reg + ig * gg;
      c_reg = cn;
      const float hn = og * ftanh(cn);
      const int row = row_base + rl, hid = mem * 16 + ul;
      const float hn2 = __shfl_down(hn, 1);
      if ((ul & 1) == 0) {
        const unsigned long long pk =
            (unsigned long long)__float_as_uint(hn) |
            (((unsigned long long)__float_as_uint(hn2)) << 32);
        AT_STORE((unsigned long long*)&hdst[(size_t)row * H_ + hid], pk);
      }
      if (t == T_ - 1) {
        out[BTVo + (size_t)row * H_ + hid] = hn;                    // h_f
        out[BTVo + (size_t)B_ * H_ + (size_t)row * H_ + hid] = cn;  // c_f
      }
    }
    __syncthreads();   // drains vmcnt -> release for hdone flag
    if (tid == 0)
      AT_STORE(&hdone[(((t & 1) * 8 + gid) * 32 + mem) * 16], t + 2);

    // ---- E: wait for all members' h(t) ----------------------------------
    if (tid < 32) {
      int* fp = &hdone[(((t & 1) * 8 + gid) * 32 + tid) * 16];
      for (int it = 0; AT_LOAD(fp) != t + 2 && it < SPIN_MAX; ++it)
        __builtin_amdgcn_s_sleep(1);
    }
    __atomic_signal_fence(__ATOMIC_ACQ_REL);
    __syncthreads();

    // ---- F: stage h(t) into hs (stride-20 chunks) -----------------------
    {
      const unsigned long long* hq =
          (const unsigned long long*)(hdst + (size_t)row_base * H_);
      unsigned long long v[4];
#pragma unroll
      for (int i = 0; i < 4; ++i) v[i] = AT_LOAD(&hq[tid + i * 1024]);
#pragma unroll
      for (int i = 0; i < 4; ++i) {
        const int idx = tid + i * 1024;
        const int row = idx >> 8, cp = idx & 255;
        *(unsigned long long*)&sm.hs[row][(cp >> 3) * 20 + (cp & 7) * 2] = v[i];
      }
    }
    __syncthreads();

    // ---- P2: logits(t) partials = Wout_quarter * h(t) -> lbuf4[par2] ----
#pragma unroll 1
    for (int r = 0; r < 16; ++r) {
      const float* hr = &sm.hs[r][hcol];
      const float4 h0 = *(const float4*)(hr + 0);
      const float4 h1 = *(const float4*)(hr + 4);
      float b0 = dot4(w2r[0][1], h1, dot4(w2r[0][0], h0, 0.f));
      float b1 = dot4(w2r[1][1], h1, dot4(w2r[1][0], h0, 0.f));
      b0 = red16(b0); b1 = red16(b1);
      if (kc < 2)
        sm.lbuf4[par2][r][blk * 8 + q1 * 2 + kc] = (kc == 0) ? b0 : b1;
    }
    __syncthreads();

    // ---- H: combine parities, write logits, argmax -> amax --------------
    if (tid < 512) {
      const int r = tid >> 5, j = tid & 31;
      float v = (sm.lbuf4[0][r][j] + sm.lbuf4[1][r][j]) +
                (sm.lbuf4[2][r][j] + sm.lbuf4[3][r][j]) + sm.sbout[j];
      if (vb + j < V_)
        out[((size_t)(row_base + r) * T_ + t) * V_ + vb + j] = v;
      else
        v = -FLT_MAX;
      int ix = j;
#pragma unroll
      for (int d = 16; d >= 1; d >>= 1) {
        const float vo = __shfl_xor(v, d, 32);
        const int   io = __shfl_xor(ix, d, 32);
        if (vo > v || (vo == v && io < ix)) { v = vo; ix = io; }
      }
      if (j == 0) {
        const unsigned long long pk =
            (((unsigned long long)__float_as_uint(v)) << 32) |
            ((unsigned)(t + 2) << 16) | (unsigned)(vb + ix);
        AT_STORE(&amax[((size_t)(t & 1) * B_ + row_base + r) * 32 + mem], pk);
      }
    }
    // no barrier: next iteration's P1 reads hs (stable until next F) and
    // writes gbuf4 (last read by D(t), separated by multiple barriers).
  }
}

// ---------------------------------------------------------------------------
extern "C" void kernel_launch(void* const* d_in, const int* in_sizes, int n_in,
                              void* d_out, int out_size, void* d_ws, size_t ws_size,
                              hipStream_t stream)
{
  const float* ctx   = (const float*)d_in[0];
  const float* emb   = (const float*)d_in[1];
  const float* Wih   = (const float*)d_in[2];
  const float* bih   = (const float*)d_in[3];
  const float* Whh   = (const float*)d_in[4];
  const float* bhh   = (const float*)d_in[5];
  const float* Wout  = (const float*)d_in[6];
  const float* bout  = (const float*)d_in[7];
  const int*   start = (const int*)d_in[8];
  float* out = (float*)d_out;

  // workspace layout (bytes)
  char* ws = (char*)d_ws;
  float* proj  = (float*)(ws + 0);                    // 1000*2048*4 = 8,192,000
  float* basep = (float*)(ws + 8192000);              // 128*2048*4  = 1,048,576
  float* hbuf  = (float*)(ws + 9240576);              // 2*128*512*4 =   524,288
  unsigned long long* amax = (unsigned long long*)(ws + 9764864);  // 2*128*32*8 = 65,536
  int*   hdone = (int*)(ws + 9830400);                // 2*8*32*64B  =    32,768

  hipLaunchKernelGGL(gemm_nt_k512, dim3(32, 2), dim3(256), 0, stream,
                     ctx, B_, Wih, 1024, 0, bih, bhh, basep, G4_, 1);
  hipLaunchKernelGGL(gemm_nt_k512, dim3(32, 16), dim3(256), 0, stream,
                     emb, V_, Wih, 1024, 512, (const float*)nullptr, (const float*)nullptr,
                     proj, G4_, 1);
  hipLaunchKernelGGL(init_kernel, dim3(64), dim3(256), 0, stream,
                     ctx, hbuf, amax, hdone, start);

  void* args[] = {(void*)&Whh, (void*)&Wout, (void*)&bout, (void*)&proj, (void*)&basep,
                  (void*)&hbuf, (void*)&amax, (void*)&hdone, (void*)&out};
  hipLaunchCooperativeKernel(reinterpret_cast<const void*>(decoder_main),
                             dim3(NBLK), dim3(1024), args, 0, stream);
}

// Round 9
// 2855.618 us; speedup vs baseline: 1.1369x; 1.1369x over previous
//
#include <hip/hip_runtime.h>
#include <float.h>
#include <math.h>

#define B_    128
#define H_    512
#define V_    1000
#define T_    256
#define G4_   2048
#define NBLK  256          // cooperative launch: 1 block/CU
#define SPIN_MAX (1 << 17) // bounded spin: converts would-be hang into wrong-answer

#define AT_LOAD(p)    __hip_atomic_load((p), __ATOMIC_RELAXED, __HIP_MEMORY_SCOPE_AGENT)
#define AT_STORE(p,v) __hip_atomic_store((p), (v), __ATOMIC_RELAXED, __HIP_MEMORY_SCOPE_AGENT)

// Pin a float4 in VGPRs (r7: kept RA from folding weight loads into the loop).
#define PIN4(v_) asm volatile("" : "+v"((v_).x), "+v"((v_).y), "+v"((v_).z), "+v"((v_).w))

__device__ __forceinline__ float dot4(float4 a, float4 b, float acc) {
  return fmaf(a.x, b.x, fmaf(a.y, b.y, fmaf(a.z, b.z, fmaf(a.w, b.w, acc))));
}

// 2-step DPP quad reduction: after this, each lane holds the sum over its
// 4-lane quad (lanes kc&~3 .. kc|3).  Replaces r7's 4-step red16 (the 16-lane
// combine's last 2 steps move to the D/H phases as cheap LDS float4 sums) --
// r8 showed reduction DPP, not FMA, dominates marginal issue cost.
__device__ __forceinline__ float red4(float x) {
  x += __int_as_float(__builtin_amdgcn_mov_dpp(__float_as_int(x), 0xB1, 0xF, 0xF, true)); // xor1
  x += __int_as_float(__builtin_amdgcn_mov_dpp(__float_as_int(x), 0x4E, 0xF, 0xF, true)); // xor2
  return x;
}

// Fast overflow-safe transcendentals (map to v_exp_f32/v_rcp_f32).
__device__ __forceinline__ float fsigmoid(float x) {
  return 1.f / (1.f + __expf(-x));
}
__device__ __forceinline__ float ftanh(float x) {
  const float e = __expf(2.f * fabsf(x));
  return copysignf(1.f - 2.f / (e + 1.f), x);
}

// ---------------------------------------------------------------------------
// Precompute GEMM:  C = A[M][0:512] * Bm[N][koff:+512]^T (+bias1+bias2).
// ileave=1 stores gate-interleaved: C[m][ (n&511)*4 + (n>>9) ]  (ldc=2048).
// ---------------------------------------------------------------------------
__global__ __launch_bounds__(256) void gemm_nt_k512(
    const float* __restrict__ A, int M,
    const float* __restrict__ Bm, int ldb, int koff,
    const float* __restrict__ bias1, const float* __restrict__ bias2,
    float* __restrict__ C, int ldc, int ileave)
{
  __shared__ float As[16][68];
  __shared__ float Bs[16][68];
  const int tid = threadIdx.x;
  const int m0 = blockIdx.y * 64, n0 = blockIdx.x * 64;
  const int tm = tid & 15, tn = tid >> 4;
  const int lm = tid & 63, kq = tid >> 6;
  float acc[4][4] = {};
  for (int k0 = 0; k0 < 512; k0 += 16) {
    float4 av = make_float4(0.f, 0.f, 0.f, 0.f);
    if (m0 + lm < M) av = *(const float4*)(A + (size_t)(m0 + lm) * 512 + k0 + kq * 4);
    float4 bv = *(const float4*)(Bm + (size_t)(n0 + lm) * ldb + koff + k0 + kq * 4);
    __syncthreads();
    As[kq*4+0][lm] = av.x; As[kq*4+1][lm] = av.y; As[kq*4+2][lm] = av.z; As[kq*4+3][lm] = av.w;
    Bs[kq*4+0][lm] = bv.x; Bs[kq*4+1][lm] = bv.y; Bs[kq*4+2][lm] = bv.z; Bs[kq*4+3][lm] = bv.w;
    __syncthreads();
#pragma unroll
    for (int kk = 0; kk < 16; ++kk) {
      const float4 a = *(const float4*)&As[kk][tm * 4];
      const float4 b = *(const float4*)&Bs[kk][tn * 4];
      const float aa[4] = {a.x, a.y, a.z, a.w};
      const float bb[4] = {b.x, b.y, b.z, b.w};
#pragma unroll
      for (int i = 0; i < 4; ++i)
#pragma unroll
        for (int j = 0; j < 4; ++j)
          acc[i][j] = fmaf(aa[i], bb[j], acc[i][j]);
    }
  }
#pragma unroll
  for (int i = 0; i < 4; ++i) {
    const int m = m0 + tm * 4 + i;
    if (m < M) {
#pragma unroll
      for (int j = 0; j < 4; ++j) {
        const int n = n0 + tn * 4 + j;
        float v = acc[i][j];
        if (bias1) v += bias1[n];
        if (bias2) v += bias2[n];
        const size_t idx = ileave ? ((size_t)m * ldc + (size_t)(n & 511) * 4 + (n >> 9))
                                  : ((size_t)m * ldc + n);
        C[idx] = v;
      }
    }
  }
}

// ---------------------------------------------------------------------------
// amax word: [val:f32 bits in high 32][tag:16][token:16]; tag(t) = t+2.
// ---------------------------------------------------------------------------
__global__ __launch_bounds__(256) void init_kernel(
    const float* __restrict__ ctx, float* __restrict__ hbuf,
    unsigned long long* __restrict__ amax,
    int* __restrict__ hdone, const int* __restrict__ start_id)
{
  const int i = blockIdx.x * blockDim.x + threadIdx.x;
  // h(-1) = context into slot 1
  ((float4*)(hbuf + B_ * H_))[i] = ((const float4*)ctx)[i];
  if (i < B_ * 32) {
    const int m = i & 31;
    const unsigned long long w = (m == 0)
        ? ((((unsigned long long)__float_as_uint(FLT_MAX)) << 32) |
           (1u << 16) | (unsigned)(*start_id))
        : ((((unsigned long long)__float_as_uint(-FLT_MAX)) << 32) | (1u << 16));
    amax[(size_t)B_ * 32 + i] = w;   // parity-1 slot, tag(-1)=1
  }
  if (i < 2 * 8 * 32) hdone[i * 16] = 0;
}

// ---------------------------------------------------------------------------
// Persistent cooperative decoder, 512 threads (8 waves, 2/SIMD) -- r7 base.
// 8 groups x 32 blocks; group g owns rows [16g,16g+16).  Tagged-dataflow sync.
//
// Round-9 changes vs r7 (3078us):
//  * red16 -> red4: P1/P2 reduce only within 4-lane quads (2 DPP steps).
//    Every lane stores ONE quad-partial into gq/lq (bijective, and the
//    [u*20 + g*4 + quad] layout makes the 64 write banks exactly 0..31 ->
//    conflict-free).  D/H finish the sum as float4 reads (+7 adds each).
//    r8 isolated reduction DPP as the dominant marginal issue cost.
//  * #pragma unroll 2 on P1/P2 row loops (addressing amortization, ILP).
//  * Everything else = r7: phase order P1->B->D->E->F->P2->H (poll hidden
//    under P1), stride-20 hs, pinned weights, fast transcendentals,
//    bounded spins + token clamp.
// ---------------------------------------------------------------------------
__global__ __launch_bounds__(512, 2) void decoder_main(
    const float* __restrict__ Whh,
    const float* __restrict__ Wout,
    const float* __restrict__ bout,
    const float* __restrict__ proj,
    const float* __restrict__ basep,
    float* __restrict__ hbuf,
    unsigned long long* __restrict__ amax,
    int* __restrict__ hdone,
    float* __restrict__ out)
{
  __shared__ struct alignas(16) SM {
    float hs[16][640];          // h tile: chunk cc at col cc*20 (16 used, 4 pad)
    float gbase[16][68];        // interleaved basep slice [r][u*4+g]
    float gq[2][16][324];       // gate quad-partials [par][r][u*20 + g*4 + quad]
    float lq[2][16][132];       // logit quad-partials [par][r][j*4 + quad]
    float sbout[32];
    int   tok[16];
  } sm;

  const int tid  = threadIdx.x;
  const int bid  = blockIdx.x;
  const int gid  = bid >> 5;     // group: rows [16g, 16g+16)
  const int mem  = bid & 31;     // member: units [16*mem,+16) / vocab [32*mem,+32)
  const int lane = tid & 63;
  const int w    = tid >> 6;     // wave 0..7
  const int row_base = gid * 16;
  const int vb   = mem * 32;

  const int q1  = lane >> 4;     // 0..3
  const int kc  = lane & 15;     // 16-float K-chunk within the K-half
  const int i3  = kc & 3;        // which output this lane stores
  const int quad = kc >> 2;      // quad-partial index
  const int blk = w & 3;         // gate index / vocab-octet
  const int par = w >> 2;        // K-half 0/1
  const int hoff  = par * 256 + kc * 16;     // K offset in weights (logical)
  const int hcol  = (par * 16 + kc) * 20;    // hs column of this chunk

  // per-lane store offsets (within a row plane)
  const int goff = (q1 * 4 + i3) * 20 + blk * 4 + quad;   // gq: conflict-free
  const int loff = (blk * 8 + q1 * 2 + i3) * 4 + quad;    // lq (i3<2 only)

  // ---- one-time preloads: weights -> registers, PINNED -------------------
  float4 w1r[4][4];              // 4 gate-lines x 16 floats = 64 VGPR
#pragma unroll
  for (int i = 0; i < 4; ++i) {
    const float* p = Whh + (size_t)(blk * 512 + mem * 16 + q1 * 4 + i) * H_ + hoff;
#pragma unroll
    for (int j = 0; j < 4; ++j) w1r[i][j] = *(const float4*)(p + j * 4);
  }
  const int v0 = vb + blk * 8 + q1 * 2;
  float4 w2r[2][4];              // 2 vocab x 16 floats = 32 VGPR
#pragma unroll
  for (int jj = 0; jj < 2; ++jj) {
    const int vv = (v0 + jj < V_) ? (v0 + jj) : (V_ - 1);
    const float* p = Wout + (size_t)vv * H_ + hoff;
#pragma unroll
    for (int j = 0; j < 4; ++j) w2r[jj][j] = *(const float4*)(p + j * 4);
  }
#pragma unroll
  for (int i = 0; i < 4; ++i) {
    PIN4(w1r[i][0]); PIN4(w1r[i][1]); PIN4(w1r[i][2]); PIN4(w1r[i][3]);
  }
#pragma unroll
  for (int jj = 0; jj < 2; ++jj) {
    PIN4(w2r[jj][0]); PIN4(w2r[jj][1]); PIN4(w2r[jj][2]); PIN4(w2r[jj][3]);
  }

  // basep slice (interleaved) -> LDS; bout slice -> LDS
#pragma unroll
  for (int kx = 0; kx < 2; ++kx) {
    const int e = tid + kx * 512;
    const int r = e >> 6, c = e & 63;
    sm.gbase[r][c] = basep[(size_t)(row_base + r) * G4_ + mem * 64 + c];
  }
  if (tid < 32) sm.sbout[tid] = (vb + tid < V_) ? bout[vb + tid] : 0.f;

  float c_reg = 0.f;   // tid<256 owns cell (row=row_base+(tid>>4), unit=mem*16+(tid&15))
  const size_t BTVo = (size_t)B_ * T_ * V_;

  // ---- prepass: stage h(-1)=context into hs (stride-20 chunks) -----------
  {
    const unsigned long long* hq =
        (const unsigned long long*)(hbuf + (size_t)B_ * H_ + (size_t)row_base * H_);
    unsigned long long v[8];
#pragma unroll
    for (int i = 0; i < 8; ++i) v[i] = AT_LOAD(&hq[tid + i * 512]);
#pragma unroll
    for (int i = 0; i < 8; ++i) {
      const int idx = tid + i * 512;
      const int row = idx >> 8, cp = idx & 255;
      *(unsigned long long*)&sm.hs[row][(cp >> 3) * 20 + (cp & 7) * 2] = v[i];
    }
  }
  __syncthreads();

  for (int t = 0; t < T_; ++t) {
    float* hdst = hbuf + (size_t)(t & 1) * (B_ * H_);

    // ---- P1: gates(t) quad-partials = Whh_half * h(t-1) -> gq[par] -------
#pragma unroll 2
    for (int r = 0; r < 16; ++r) {
      const float* hr = &sm.hs[r][hcol];
      const float4 h0 = *(const float4*)(hr + 0);
      const float4 h1 = *(const float4*)(hr + 4);
      const float4 h2 = *(const float4*)(hr + 8);
      const float4 h3 = *(const float4*)(hr + 12);
      float a0 = dot4(w1r[0][3], h3, dot4(w1r[0][2], h2, dot4(w1r[0][1], h1, dot4(w1r[0][0], h0, 0.f))));
      float a1 = dot4(w1r[1][3], h3, dot4(w1r[1][2], h2, dot4(w1r[1][1], h1, dot4(w1r[1][0], h0, 0.f))));
      float a2 = dot4(w1r[2][3], h3, dot4(w1r[2][2], h2, dot4(w1r[2][1], h1, dot4(w1r[2][0], h0, 0.f))));
      float a3 = dot4(w1r[3][3], h3, dot4(w1r[3][2], h2, dot4(w1r[3][1], h1, dot4(w1r[3][0], h0, 0.f))));
      a0 = red4(a0); a1 = red4(a1); a2 = red4(a2); a3 = red4(a3);
      const float av = (i3 == 0) ? a0 : (i3 == 1) ? a1 : (i3 == 2) ? a2 : a3;
      sm.gq[par][r][goff] = av;
    }

    // ---- B: poll amax(t-1) -> tok[]  (propagation hidden under P1) ------
    {
      const int prow = tid >> 5, pj = tid & 31;
      const unsigned expect = (unsigned)(t + 1) << 16;   // tag(t-1) = t+1
      const unsigned long long* ap =
          amax + ((size_t)((t + 1) & 1) * B_ + row_base + prow) * 32;
      unsigned long long wv = AT_LOAD(&ap[pj]);
      for (int it = 0; (((unsigned)wv ^ expect) & 0xFFFF0000u) && it < SPIN_MAX; ++it) {
        __builtin_amdgcn_s_sleep(1);
        wv = AT_LOAD(&ap[pj]);
      }
      __atomic_signal_fence(__ATOMIC_ACQ_REL);
      float v  = __uint_as_float((unsigned)(wv >> 32));
      int   ix = (int)((unsigned)wv & 0xFFFFu);
#pragma unroll
      for (int d = 16; d >= 1; d >>= 1) {
        const float vo = __shfl_xor(v, d, 32);
        const int   io = __shfl_xor(ix, d, 32);
        if (vo > v || (vo == v && io < ix)) { v = vo; ix = io; }
      }
      if (pj == 0) sm.tok[prow] = (ix >= 0 && ix < V_) ? ix : 0;   // clamp
    }
    __syncthreads();

    // ---- D: LSTM epilogue (tid<256): sum 8 quad-partials + proj + gbase --
    if (tid < 256) {
      const int rl = tid >> 4, ul = tid & 15;
      const int tk = sm.tok[rl];
      float gate[4];
#pragma unroll
      for (int g = 0; g < 4; ++g) {
        const float4 qa = *(const float4*)&sm.gq[0][rl][ul * 20 + g * 4];
        const float4 qb = *(const float4*)&sm.gq[1][rl][ul * 20 + g * 4];
        gate[g] = ((qa.x + qa.y) + (qa.z + qa.w)) + ((qb.x + qb.y) + (qb.z + qb.w));
      }
      const float4 gc = *(const float4*)&sm.gbase[rl][ul * 4];
      const float4 gp = *(const float4*)&proj[(size_t)tk * G4_ + (size_t)(mem * 16 + ul) * 4];
      const float gx = gate[0] + gc.x + gp.x;
      const float gy = gate[1] + gc.y + gp.y;
      const float gz = gate[2] + gc.z + gp.z;
      const float gw = gate[3] + gc.w + gp.w;
      const float ig = fsigmoid(gx);
      const float fg = fsigmoid(gy);
      const float gg = ftanh(gz);
      const float og = fsigmoid(gw);
      const float cn = fg * c_reg + ig * gg;
      c_reg = cn;
      const float hn = og * ftanh(cn);
      const int row = row_base + rl, hid = mem * 16 + ul;
      const float hn2 = __shfl_down(hn, 1);
      if ((ul & 1) == 0) {
        const unsigned long long pk =
            (unsigned long long)__float_as_uint(hn) |
            (((unsigned long long)__float_as_uint(hn2)) << 32);
        AT_STORE((unsigned long long*)&hdst[(size_t)row * H_ + hid], pk);
      }
      if (t == T_ - 1) {
        out[BTVo + (size_t)row * H_ + hid] = hn;                    // h_f
        out[BTVo + (size_t)B_ * H_ + (size_t)row * H_ + hid] = cn;  // c_f
      }
    }
    __syncthreads();   // drains vmcnt -> release for hdone flag
    if (tid == 0)
      AT_STORE(&hdone[(((t & 1) * 8 + gid) * 32 + mem) * 16], t + 2);

    // ---- E: wait for all members' h(t) ----------------------------------
    if (tid < 32) {
      int* fp = &hdone[(((t & 1) * 8 + gid) * 32 + tid) * 16];
      for (int it = 0; AT_LOAD(fp) != t + 2 && it < SPIN_MAX; ++it)
        __builtin_amdgcn_s_sleep(1);
    }
    __atomic_signal_fence(__ATOMIC_ACQ_REL);
    __syncthreads();

    // ---- F: stage h(t) into hs (stride-20 chunks) -----------------------
    {
      const unsigned long long* hq =
          (const unsigned long long*)(hdst + (size_t)row_base * H_);
      unsigned long long v[8];
#pragma unroll
      for (int i = 0; i < 8; ++i) v[i] = AT_LOAD(&hq[tid + i * 512]);
#pragma unroll
      for (int i = 0; i < 8; ++i) {
        const int idx = tid + i * 512;
        const int row = idx >> 8, cp = idx & 255;
        *(unsigned long long*)&sm.hs[row][(cp >> 3) * 20 + (cp & 7) * 2] = v[i];
      }
    }
    __syncthreads();

    // ---- P2: logits(t) quad-partials = Wout_half * h(t) -> lq[par] ------
#pragma unroll 2
    for (int r = 0; r < 16; ++r) {
      const float* hr = &sm.hs[r][hcol];
      const float4 h0 = *(const float4*)(hr + 0);
      const float4 h1 = *(const float4*)(hr + 4);
      const float4 h2 = *(const float4*)(hr + 8);
      const float4 h3 = *(const float4*)(hr + 12);
      float b0 = dot4(w2r[0][3], h3, dot4(w2r[0][2], h2, dot4(w2r[0][1], h1, dot4(w2r[0][0], h0, 0.f))));
      float b1 = dot4(w2r[1][3], h3, dot4(w2r[1][2], h2, dot4(w2r[1][1], h1, dot4(w2r[1][0], h0, 0.f))));
      b0 = red4(b0); b1 = red4(b1);
      if (i3 < 2)
        sm.lq[par][r][loff] = (i3 == 0) ? b0 : b1;
    }
    __syncthreads();

    // ---- H: sum 8 quad-partials, write logits, argmax -> amax -----------
    {
      const int r = tid >> 5, j = tid & 31;
      const float4 qa = *(const float4*)&sm.lq[0][r][j * 4];
      const float4 qb = *(const float4*)&sm.lq[1][r][j * 4];
      float v = ((qa.x + qa.y) + (qa.z + qa.w)) +
                ((qb.x + qb.y) + (qb.z + qb.w)) + sm.sbout[j];
      if (vb + j < V_)
        out[((size_t)(row_base + r) * T_ + t) * V_ + vb + j] = v;
      else
        v = -FLT_MAX;
      int ix = j;
#pragma unroll
      for (int d = 16; d >= 1; d >>= 1) {
        const float vo = __shfl_xor(v, d, 32);
        const int   io = __shfl_xor(ix, d, 32);
        if (vo > v || (vo == v && io < ix)) { v = vo; ix = io; }
      }
      if (j == 0) {
        const unsigned long long pk =
            (((unsigned long long)__float_as_uint(v)) << 32) |
            ((unsigned)(t + 2) << 16) | (unsigned)(vb + ix);
        AT_STORE(&amax[((size_t)(t & 1) * B_ + row_base + r) * 32 + mem], pk);
      }
    }
    // no barrier: next iteration's P1 reads hs (stable until next F) and
    // writes gq (last read by D(t), separated by multiple barriers).
  }
}

// ---------------------------------------------------------------------------
extern "C" void kernel_launch(void* const* d_in, const int* in_sizes, int n_in,
                              void* d_out, int out_size, void* d_ws, size_t ws_size,
                              hipStream_t stream)
{
  const float* ctx   = (const float*)d_in[0];
  const float* emb   = (const float*)d_in[1];
  const float* Wih   = (const float*)d_in[2];
  const float* bih   = (const float*)d_in[3];
  const float* Whh   = (const float*)d_in[4];
  const float* bhh   = (const float*)d_in[5];
  const float* Wout  = (const float*)d_in[6];
  const float* bout  = (const float*)d_in[7];
  const int*   start = (const int*)d_in[8];
  float* out = (float*)d_out;

  // workspace layout (bytes)
  char* ws = (char*)d_ws;
  float* proj  = (float*)(ws + 0);                    // 1000*2048*4 = 8,192,000
  float* basep = (float*)(ws + 8192000);              // 128*2048*4  = 1,048,576
  float* hbuf  = (float*)(ws + 9240576);              // 2*128*512*4 =   524,288
  unsigned long long* amax = (unsigned long long*)(ws + 9764864);  // 2*128*32*8 = 65,536
  int*   hdone = (int*)(ws + 9830400);                // 2*8*32*64B  =    32,768

  hipLaunchKernelGGL(gemm_nt_k512, dim3(32, 2), dim3(256), 0, stream,
                     ctx, B_, Wih, 1024, 0, bih, bhh, basep, G4_, 1);
  hipLaunchKernelGGL(gemm_nt_k512, dim3(32, 16), dim3(256), 0, stream,
                     emb, V_, Wih, 1024, 512, (const float*)nullptr, (const float*)nullptr,
                     proj, G4_, 1);
  hipLaunchKernelGGL(init_kernel, dim3(64), dim3(256), 0, stream,
                     ctx, hbuf, amax, hdone, start);

  void* args[] = {(void*)&Whh, (void*)&Wout, (void*)&bout, (void*)&proj, (void*)&basep,
                  (void*)&hbuf, (void*)&amax, (void*)&hdone, (void*)&out};
  hipLaunchCooperativeKernel(reinterpret_cast<const void*>(decoder_main),
                             dim3(NBLK), dim3(512), args, 0, stream);
}

// Round 10
// 2695.506 us; speedup vs baseline: 1.2044x; 1.0594x over previous
//
#include <hip/hip_runtime.h>
#include <float.h>
#include <math.h>

#define B_    128
#define H_    512
#define V_    1000
#define T_    256
#define G4_   2048
#define NBLK  256          // cooperative launch: 1 block/CU
#define SPIN_MAX (1 << 17) // bounded spin: converts would-be hang into wrong-answer

#define AT_LOAD(p)    __hip_atomic_load((p), __ATOMIC_RELAXED, __HIP_MEMORY_SCOPE_AGENT)
#define AT_STORE(p,v) __hip_atomic_store((p), (v), __ATOMIC_RELAXED, __HIP_MEMORY_SCOPE_AGENT)

// Packed-fp32 vector type: float2 arithmetic contracts to v_pk_fma_f32 on
// gfx950 (VOP3P packed FP32, CDNA2+), halving FMA issue count vs scalar fmaf.
typedef float f2 __attribute__((ext_vector_type(2)));

// Pin a 64-bit f2 in a VGPR pair (whole-value constraint keeps RA pairing;
// r7 evidence: without pinning, weight loads get rematerialized into the loop).
#define PINF2(v_) asm volatile("" : "+v"(v_))

// 2-step DPP quad reduction (r9): lane holds sum over its 4-lane quad.
__device__ __forceinline__ float red4(float x) {
  x += __int_as_float(__builtin_amdgcn_mov_dpp(__float_as_int(x), 0xB1, 0xF, 0xF, true)); // xor1
  x += __int_as_float(__builtin_amdgcn_mov_dpp(__float_as_int(x), 0x4E, 0xF, 0xF, true)); // xor2
  return x;
}

// Fast overflow-safe transcendentals (map to v_exp_f32/v_rcp_f32).
__device__ __forceinline__ float fsigmoid(float x) {
  return 1.f / (1.f + __expf(-x));
}
__device__ __forceinline__ float ftanh(float x) {
  const float e = __expf(2.f * fabsf(x));
  return copysignf(1.f - 2.f / (e + 1.f), x);
}

// ---------------------------------------------------------------------------
// Precompute GEMM:  C = A[M][0:512] * Bm[N][koff:+512]^T (+bias1+bias2).
// ileave=1 stores gate-interleaved: C[m][ (n&511)*4 + (n>>9) ]  (ldc=2048).
// ---------------------------------------------------------------------------
__global__ __launch_bounds__(256) void gemm_nt_k512(
    const float* __restrict__ A, int M,
    const float* __restrict__ Bm, int ldb, int koff,
    const float* __restrict__ bias1, const float* __restrict__ bias2,
    float* __restrict__ C, int ldc, int ileave)
{
  __shared__ float As[16][68];
  __shared__ float Bs[16][68];
  const int tid = threadIdx.x;
  const int m0 = blockIdx.y * 64, n0 = blockIdx.x * 64;
  const int tm = tid & 15, tn = tid >> 4;
  const int lm = tid & 63, kq = tid >> 6;
  float acc[4][4] = {};
  for (int k0 = 0; k0 < 512; k0 += 16) {
    float4 av = make_float4(0.f, 0.f, 0.f, 0.f);
    if (m0 + lm < M) av = *(const float4*)(A + (size_t)(m0 + lm) * 512 + k0 + kq * 4);
    float4 bv = *(const float4*)(Bm + (size_t)(n0 + lm) * ldb + koff + k0 + kq * 4);
    __syncthreads();
    As[kq*4+0][lm] = av.x; As[kq*4+1][lm] = av.y; As[kq*4+2][lm] = av.z; As[kq*4+3][lm] = av.w;
    Bs[kq*4+0][lm] = bv.x; Bs[kq*4+1][lm] = bv.y; Bs[kq*4+2][lm] = bv.z; Bs[kq*4+3][lm] = bv.w;
    __syncthreads();
#pragma unroll
    for (int kk = 0; kk < 16; ++kk) {
      const float4 a = *(const float4*)&As[kk][tm * 4];
      const float4 b = *(const float4*)&Bs[kk][tn * 4];
      const float aa[4] = {a.x, a.y, a.z, a.w};
      const float bb[4] = {b.x, b.y, b.z, b.w};
#pragma unroll
      for (int i = 0; i < 4; ++i)
#pragma unroll
        for (int j = 0; j < 4; ++j)
          acc[i][j] = fmaf(aa[i], bb[j], acc[i][j]);
    }
  }
#pragma unroll
  for (int i = 0; i < 4; ++i) {
    const int m = m0 + tm * 4 + i;
    if (m < M) {
#pragma unroll
      for (int j = 0; j < 4; ++j) {
        const int n = n0 + tn * 4 + j;
        float v = acc[i][j];
        if (bias1) v += bias1[n];
        if (bias2) v += bias2[n];
        const size_t idx = ileave ? ((size_t)m * ldc + (size_t)(n & 511) * 4 + (n >> 9))
                                  : ((size_t)m * ldc + n);
        C[idx] = v;
      }
    }
  }
}

// ---------------------------------------------------------------------------
// amax word: [val:f32 bits in high 32][tag:16][token:16]; tag(t) = t+2.
// ---------------------------------------------------------------------------
__global__ __launch_bounds__(256) void init_kernel(
    const float* __restrict__ ctx, float* __restrict__ hbuf,
    unsigned long long* __restrict__ amax,
    int* __restrict__ hdone, const int* __restrict__ start_id)
{
  const int i = blockIdx.x * blockDim.x + threadIdx.x;
  // h(-1) = context into slot 1
  ((float4*)(hbuf + B_ * H_))[i] = ((const float4*)ctx)[i];
  if (i < B_ * 32) {
    const int m = i & 31;
    const unsigned long long w = (m == 0)
        ? ((((unsigned long long)__float_as_uint(FLT_MAX)) << 32) |
           (1u << 16) | (unsigned)(*start_id))
        : ((((unsigned long long)__float_as_uint(-FLT_MAX)) << 32) | (1u << 16));
    amax[(size_t)B_ * 32 + i] = w;   // parity-1 slot, tag(-1)=1
  }
  if (i < 2 * 8 * 32) hdone[i * 16] = 0;
}

// ---------------------------------------------------------------------------
// Persistent cooperative decoder, 512 threads (8 waves, 2/SIMD) -- r9 base.
// 8 groups x 32 blocks; group g owns rows [16g,16g+16).  Tagged-dataflow sync.
//
// Round-10 change vs r9 (2856us): P1/P2 dot products converted to float2
// (f2) arithmetic -> v_pk_fma_f32 (2 FMA/inst).  P1: 32 pk_fma + 4 horiz
// adds (was 64 fmaf); P2: 16 (was 32).  Weights live as pinned f2 pairs
// (same 96-VGPR footprint).  Everything else identical to r9: red4 quad
// reduction + gq/lq combine planes, stride-20 hs, phase order
// P1->B->D->E->F->P2->H, fast transcendentals, bounded spins + token clamp.
// ---------------------------------------------------------------------------
__global__ __launch_bounds__(512, 2) void decoder_main(
    const float* __restrict__ Whh,
    const float* __restrict__ Wout,
    const float* __restrict__ bout,
    const float* __restrict__ proj,
    const float* __restrict__ basep,
    float* __restrict__ hbuf,
    unsigned long long* __restrict__ amax,
    int* __restrict__ hdone,
    float* __restrict__ out)
{
  __shared__ struct alignas(16) SM {
    float hs[16][640];          // h tile: chunk cc at col cc*20 (16 used, 4 pad)
    float gbase[16][68];        // interleaved basep slice [r][u*4+g]
    float gq[2][16][324];       // gate quad-partials [par][r][u*20 + g*4 + quad]
    float lq[2][16][132];       // logit quad-partials [par][r][j*4 + quad]
    float sbout[32];
    int   tok[16];
  } sm;

  const int tid  = threadIdx.x;
  const int bid  = blockIdx.x;
  const int gid  = bid >> 5;     // group: rows [16g, 16g+16)
  const int mem  = bid & 31;     // member: units [16*mem,+16) / vocab [32*mem,+32)
  const int lane = tid & 63;
  const int w    = tid >> 6;     // wave 0..7
  const int row_base = gid * 16;
  const int vb   = mem * 32;

  const int q1  = lane >> 4;     // 0..3
  const int kc  = lane & 15;     // 16-float K-chunk within the K-half
  const int i3  = kc & 3;        // which output this lane stores
  const int quad = kc >> 2;      // quad-partial index
  const int blk = w & 3;         // gate index / vocab-octet
  const int par = w >> 2;        // K-half 0/1
  const int hoff  = par * 256 + kc * 16;     // K offset in weights (logical)
  const int hcol  = (par * 16 + kc) * 20;    // hs column of this chunk

  // per-lane store offsets (within a row plane)
  const int goff = (q1 * 4 + i3) * 20 + blk * 4 + quad;   // gq: conflict-free
  const int loff = (blk * 8 + q1 * 2 + i3) * 4 + quad;    // lq (i3<2 only)

  // ---- one-time preloads: weights -> f2 register pairs, PINNED -----------
  f2 w1p[4][8];                  // 4 gate-lines x 16 floats = 64 VGPR
#pragma unroll
  for (int i = 0; i < 4; ++i) {
    const f2* p = (const f2*)(Whh + (size_t)(blk * 512 + mem * 16 + q1 * 4 + i) * H_ + hoff);
#pragma unroll
    for (int j = 0; j < 8; ++j) w1p[i][j] = p[j];
  }
  const int v0 = vb + blk * 8 + q1 * 2;
  f2 w2p[2][8];                  // 2 vocab x 16 floats = 32 VGPR
#pragma unroll
  for (int jj = 0; jj < 2; ++jj) {
    const int vv = (v0 + jj < V_) ? (v0 + jj) : (V_ - 1);
    const f2* p = (const f2*)(Wout + (size_t)vv * H_ + hoff);
#pragma unroll
    for (int j = 0; j < 8; ++j) w2p[jj][j] = p[j];
  }
#pragma unroll
  for (int i = 0; i < 4; ++i)
#pragma unroll
    for (int j = 0; j < 8; ++j) PINF2(w1p[i][j]);
#pragma unroll
  for (int jj = 0; jj < 2; ++jj)
#pragma unroll
    for (int j = 0; j < 8; ++j) PINF2(w2p[jj][j]);

  // basep slice (interleaved) -> LDS; bout slice -> LDS
#pragma unroll
  for (int kx = 0; kx < 2; ++kx) {
    const int e = tid + kx * 512;
    const int r = e >> 6, c = e & 63;
    sm.gbase[r][c] = basep[(size_t)(row_base + r) * G4_ + mem * 64 + c];
  }
  if (tid < 32) sm.sbout[tid] = (vb + tid < V_) ? bout[vb + tid] : 0.f;

  float c_reg = 0.f;   // tid<256 owns cell (row=row_base+(tid>>4), unit=mem*16+(tid&15))
  const size_t BTVo = (size_t)B_ * T_ * V_;

  // ---- prepass: stage h(-1)=context into hs (stride-20 chunks) -----------
  {
    const unsigned long long* hq =
        (const unsigned long long*)(hbuf + (size_t)B_ * H_ + (size_t)row_base * H_);
    unsigned long long v[8];
#pragma unroll
    for (int i = 0; i < 8; ++i) v[i] = AT_LOAD(&hq[tid + i * 512]);
#pragma unroll
    for (int i = 0; i < 8; ++i) {
      const int idx = tid + i * 512;
      const int row = idx >> 8, cp = idx & 255;
      *(unsigned long long*)&sm.hs[row][(cp >> 3) * 20 + (cp & 7) * 2] = v[i];
    }
  }
  __syncthreads();

  for (int t = 0; t < T_; ++t) {
    float* hdst = hbuf + (size_t)(t & 1) * (B_ * H_);

    // ---- P1: gates(t) quad-partials = Whh_half * h(t-1) -> gq[par] -------
#pragma unroll 2
    for (int r = 0; r < 16; ++r) {
      const f2* hr = (const f2*)&sm.hs[r][hcol];
      f2 c0 = {0.f, 0.f}, c1 = {0.f, 0.f}, c2 = {0.f, 0.f}, c3 = {0.f, 0.f};
#pragma unroll
      for (int j = 0; j < 8; ++j) {
        const f2 hv = hr[j];
        c0 = w1p[0][j] * hv + c0;   // v_pk_fma_f32
        c1 = w1p[1][j] * hv + c1;
        c2 = w1p[2][j] * hv + c2;
        c3 = w1p[3][j] * hv + c3;
      }
      float a0 = c0.x + c0.y;
      float a1 = c1.x + c1.y;
      float a2 = c2.x + c2.y;
      float a3 = c3.x + c3.y;
      a0 = red4(a0); a1 = red4(a1); a2 = red4(a2); a3 = red4(a3);
      const float av = (i3 == 0) ? a0 : (i3 == 1) ? a1 : (i3 == 2) ? a2 : a3;
      sm.gq[par][r][goff] = av;
    }

    // ---- B: poll amax(t-1) -> tok[]  (propagation hidden under P1) ------
    {
      const int prow = tid >> 5, pj = tid & 31;
      const unsigned expect = (unsigned)(t + 1) << 16;   // tag(t-1) = t+1
      const unsigned long long* ap =
          amax + ((size_t)((t + 1) & 1) * B_ + row_base + prow) * 32;
      unsigned long long wv = AT_LOAD(&ap[pj]);
      for (int it = 0; (((unsigned)wv ^ expect) & 0xFFFF0000u) && it < SPIN_MAX; ++it) {
        __builtin_amdgcn_s_sleep(1);
        wv = AT_LOAD(&ap[pj]);
      }
      __atomic_signal_fence(__ATOMIC_ACQ_REL);
      float v  = __uint_as_float((unsigned)(wv >> 32));
      int   ix = (int)((unsigned)wv & 0xFFFFu);
#pragma unroll
      for (int d = 16; d >= 1; d >>= 1) {
        const float vo = __shfl_xor(v, d, 32);
        const int   io = __shfl_xor(ix, d, 32);
        if (vo > v || (vo == v && io < ix)) { v = vo; ix = io; }
      }
      if (pj == 0) sm.tok[prow] = (ix >= 0 && ix < V_) ? ix : 0;   // clamp
    }
    __syncthreads();

    // ---- D: LSTM epilogue (tid<256): sum 8 quad-partials + proj + gbase --
    if (tid < 256) {
      const int rl = tid >> 4, ul = tid & 15;
      const int tk = sm.tok[rl];
      float gate[4];
#pragma unroll
      for (int g = 0; g < 4; ++g) {
        const float4 qa = *(const float4*)&sm.gq[0][rl][ul * 20 + g * 4];
        const float4 qb = *(const float4*)&sm.gq[1][rl][ul * 20 + g * 4];
        gate[g] = ((qa.x + qa.y) + (qa.z + qa.w)) + ((qb.x + qb.y) + (qb.z + qb.w));
      }
      const float4 gc = *(const float4*)&sm.gbase[rl][ul * 4];
      const float4 gp = *(const float4*)&proj[(size_t)tk * G4_ + (size_t)(mem * 16 + ul) * 4];
      const float gx = gate[0] + gc.x + gp.x;
      const float gy = gate[1] + gc.y + gp.y;
      const float gz = gate[2] + gc.z + gp.z;
      const float gw = gate[3] + gc.w + gp.w;
      const float ig = fsigmoid(gx);
      const float fg = fsigmoid(gy);
      const float gg = ftanh(gz);
      const float og = fsigmoid(gw);
      const float cn = fg * c_reg + ig * gg;
      c_reg = cn;
      const float hn = og * ftanh(cn);
      const int row = row_base + rl, hid = mem * 16 + ul;
      const float hn2 = __shfl_down(hn, 1);
      if ((ul & 1) == 0) {
        const unsigned long long pk =
            (unsigned long long)__float_as_uint(hn) |
            (((unsigned long long)__float_as_uint(hn2)) << 32);
        AT_STORE((unsigned long long*)&hdst[(size_t)row * H_ + hid], pk);
      }
      if (t == T_ - 1) {
        out[BTVo + (size_t)row * H_ + hid] = hn;                    // h_f
        out[BTVo + (size_t)B_ * H_ + (size_t)row * H_ + hid] = cn;  // c_f
      }
    }
    __syncthreads();   // drains vmcnt -> release for hdone flag
    if (tid == 0)
      AT_STORE(&hdone[(((t & 1) * 8 + gid) * 32 + mem) * 16], t + 2);

    // ---- E: wait for all members' h(t) ----------------------------------
    if (tid < 32) {
      int* fp = &hdone[(((t & 1) * 8 + gid) * 32 + tid) * 16];
      for (int it = 0; AT_LOAD(fp) != t + 2 && it < SPIN_MAX; ++it)
        __builtin_amdgcn_s_sleep(1);
    }
    __atomic_signal_fence(__ATOMIC_ACQ_REL);
    __syncthreads();

    // ---- F: stage h(t) into hs (stride-20 chunks) -----------------------
    {
      const unsigned long long* hq =
          (const unsigned long long*)(hdst + (size_t)row_base * H_);
      unsigned long long v[8];
#pragma unroll
      for (int i = 0; i < 8; ++i) v[i] = AT_LOAD(&hq[tid + i * 512]);
#pragma unroll
      for (int i = 0; i < 8; ++i) {
        const int idx = tid + i * 512;
        const int row = idx >> 8, cp = idx & 255;
        *(unsigned long long*)&sm.hs[row][(cp >> 3) * 20 + (cp & 7) * 2] = v[i];
      }
    }
    __syncthreads();

    // ---- P2: logits(t) quad-partials = Wout_half * h(t) -> lq[par] ------
#pragma unroll 2
    for (int r = 0; r < 16; ++r) {
      const f2* hr = (const f2*)&sm.hs[r][hcol];
      f2 c0 = {0.f, 0.f}, c1 = {0.f, 0.f};
#pragma unroll
      for (int j = 0; j < 8; ++j) {
        const f2 hv = hr[j];
        c0 = w2p[0][j] * hv + c0;   // v_pk_fma_f32
        c1 = w2p[1][j] * hv + c1;
      }
      float b0 = c0.x + c0.y;
      float b1 = c1.x + c1.y;
      b0 = red4(b0); b1 = red4(b1);
      if (i3 < 2)
        sm.lq[par][r][loff] = (i3 == 0) ? b0 : b1;
    }
    __syncthreads();

    // ---- H: sum 8 quad-partials, write logits, argmax -> amax -----------
    {
      const int r = tid >> 5, j = tid & 31;
      const float4 qa = *(const float4*)&sm.lq[0][r][j * 4];
      const float4 qb = *(const float4*)&sm.lq[1][r][j * 4];
      float v = ((qa.x + qa.y) + (qa.z + qa.w)) +
                ((qb.x + qb.y) + (qb.z + qb.w)) + sm.sbout[j];
      if (vb + j < V_)
        out[((size_t)(row_base + r) * T_ + t) * V_ + vb + j] = v;
      else
        v = -FLT_MAX;
      int ix = j;
#pragma unroll
      for (int d = 16; d >= 1; d >>= 1) {
        const float vo = __shfl_xor(v, d, 32);
        const int   io = __shfl_xor(ix, d, 32);
        if (vo > v || (vo == v && io < ix)) { v = vo; ix = io; }
      }
      if (j == 0) {
        const unsigned long long pk =
            (((unsigned long long)__float_as_uint(v)) << 32) |
            ((unsigned)(t + 2) << 16) | (unsigned)(vb + ix);
        AT_STORE(&amax[((size_t)(t & 1) * B_ + row_base + r) * 32 + mem], pk);
      }
    }
    // no barrier: next iteration's P1 reads hs (stable until next F) and
    // writes gq (last read by D(t), separated by multiple barriers).
  }
}

// ---------------------------------------------------------------------------
extern "C" void kernel_launch(void* const* d_in, const int* in_sizes, int n_in,
                              void* d_out, int out_size, void* d_ws, size_t ws_size,
                              hipStream_t stream)
{
  const float* ctx   = (const float*)d_in[0];
  const float* emb   = (const float*)d_in[1];
  const float* Wih   = (const float*)d_in[2];
  const float* bih   = (const float*)d_in[3];
  const float* Whh   = (const float*)d_in[4];
  const float* bhh   = (const float*)d_in[5];
  const float* Wout  = (const float*)d_in[6];
  const float* bout  = (const float*)d_in[7];
  const int*   start = (const int*)d_in[8];
  float* out = (float*)d_out;

  // workspace layout (bytes)
  char* ws = (char*)d_ws;
  float* proj  = (float*)(ws + 0);                    // 1000*2048*4 = 8,192,000
  float* basep = (float*)(ws + 8192000);              // 128*2048*4  = 1,048,576
  float* hbuf  = (float*)(ws + 9240576);              // 2*128*512*4 =   524,288
  unsigned long long* amax = (unsigned long long*)(ws + 9764864);  // 2*128*32*8 = 65,536
  int*   hdone = (int*)(ws + 9830400);                // 2*8*32*64B  =    32,768

  hipLaunchKernelGGL(gemm_nt_k512, dim3(32, 2), dim3(256), 0, stream,
                     ctx, B_, Wih, 1024, 0, bih, bhh, basep, G4_, 1);
  hipLaunchKernelGGL(gemm_nt_k512, dim3(32, 16), dim3(256), 0, stream,
                     emb, V_, Wih, 1024, 512, (const float*)nullptr, (const float*)nullptr,
                     proj, G4_, 1);
  hipLaunchKernelGGL(init_kernel, dim3(64), dim3(256), 0, stream,
                     ctx, hbuf, amax, hdone, start);

  void* args[] = {(void*)&Whh, (void*)&Wout, (void*)&bout, (void*)&proj, (void*)&basep,
                  (void*)&hbuf, (void*)&amax, (void*)&hdone, (void*)&out};
  hipLaunchCooperativeKernel(reinterpret_cast<const void*>(decoder_main),
                             dim3(NBLK), dim3(512), args, 0, stream);
}